// Round 8
// baseline (1396.834 us; speedup 1.0000x reference)
//
#include <hip/hip_runtime.h>
#include <hip/hip_fp16.h>

#define NSEQ 8192
#define DIM  512
#define VPITCH 8256            // f16 elems per XhT row (kills pow2 stride)

typedef _Float16 f16;
typedef _Float16 f16x8 __attribute__((ext_vector_type(8)));
typedef _Float16 f16x4 __attribute__((ext_vector_type(4)));
typedef float    f32x4 __attribute__((ext_vector_type(4)));

// ---------------------------------------------------------------------------
// X (fp32) -> Xh + Xl (f16 hi/lo split), elementwise.
// ---------------------------------------------------------------------------
__global__ __launch_bounds__(256) void k_splitx(const float* __restrict__ X,
                                                f16* __restrict__ Xh,
                                                f16* __restrict__ Xl)
{
  const size_t idx = (size_t)blockIdx.x * 256 + threadIdx.x;
  f32x4 v = *(const f32x4*)(X + idx * 4);
  f16x4 h, l;
#pragma unroll
  for (int i = 0; i < 4; ++i) {
    h[i] = (f16)v[i];
    l[i] = (f16)(v[i] - (float)h[i]);
  }
  *(f16x4*)(Xh + idx * 4) = h;
  *(f16x4*)(Xl + idx * 4) = l;
}

// ---------------------------------------------------------------------------
// W (512x512 fp32) -> Wt^T split: Wth/Wtl[c][k] = split(W[k][c]).
// ---------------------------------------------------------------------------
__global__ __launch_bounds__(256) void k_splitwt(const float* __restrict__ W,
                                                 f16* __restrict__ Th,
                                                 f16* __restrict__ Tl)
{
  __shared__ float T[64][65];
  const int tid = threadIdx.x;
  const int k0 = blockIdx.x * 64;
  const int c0 = blockIdx.y * 64;
#pragma unroll
  for (int e = 0; e < 16; ++e) {
    int idx = tid + e * 256;
    T[idx >> 6][idx & 63] = W[(size_t)(k0 + (idx >> 6)) * DIM + c0 + (idx & 63)];
  }
  __syncthreads();
#pragma unroll
  for (int e = 0; e < 16; ++e) {
    int idx = tid + e * 256;
    int cc = idx >> 6, kk = idx & 63;
    float v = T[kk][cc];
    f16 h = (f16)v;
    Th[(size_t)(c0 + cc) * DIM + k0 + kk] = h;
    Tl[(size_t)(c0 + cc) * DIM + k0 + kk] = (f16)(v - (float)h);
  }
}

// ---------------------------------------------------------------------------
// X -> XhT row-major [d][j], pitch VPITCH (V operand for the PV phase).
// ---------------------------------------------------------------------------
__global__ __launch_bounds__(256) void k_xt(const float* __restrict__ X,
                                            f16* __restrict__ XhT)
{
  __shared__ float T[64][65];
  const int tid = threadIdx.x;
  const int j0 = blockIdx.x * 64;
  const int d0 = blockIdx.y * 64;
#pragma unroll
  for (int e = 0; e < 16; ++e) {
    int idx = tid + e * 256;
    T[idx >> 6][idx & 63] = X[(size_t)(j0 + (idx >> 6)) * DIM + d0 + (idx & 63)];
  }
  __syncthreads();
#pragma unroll
  for (int e = 0; e < 16; ++e) {
    int idx = tid + e * 256;
    int dd = idx >> 6, jj = idx & 63;
    XhT[(size_t)(d0 + dd) * VPITCH + j0 + jj] = (f16)T[jj][dd];
  }
}

// ---------------------------------------------------------------------------
// Projection via split-f16 MFMA: C = X W  (M=8192, N=512, K=512).
// 128x128 tile, 4 waves, BK=32, 3-term split, XOR-swizzled LDS.
// Epilogue: c *= scale, split into Oh (f16 hi) + Ol (f16 lo), row-major DIM.
// ---------------------------------------------------------------------------
__global__ __launch_bounds__(256) void k_proj(
    const f16* __restrict__ Xh, const f16* __restrict__ Xl,
    const f16* __restrict__ Wth, const f16* __restrict__ Wtl,
    f16* __restrict__ Oh, f16* __restrict__ Ol, float scale)
{
  __shared__ char sm[4 * 8192];
  const int tid  = threadIdx.x;
  const int lane = tid & 63;
  const int w    = tid >> 6;
  const int wm   = (w >> 1) * 64;
  const int wn   = (w & 1) * 64;
  const int row0g = blockIdx.x * 128;
  const int col0g = blockIdx.y * 128;

  const int r1 = tid >> 2;
  const int o1 = (tid & 3) * 8;
  const int sw1 = (r1 * 64 + (tid & 3) * 16) ^ ((r1 & 7) << 4);
  const int sw2 = ((r1 + 64) * 64 + (tid & 3) * 16) ^ (((r1 + 64) & 7) << 4);
  const f16* pAh = Xh  + (size_t)(row0g + r1) * DIM + o1;
  const f16* pAl = Xl  + (size_t)(row0g + r1) * DIM + o1;
  const f16* pBh = Wth + (size_t)(col0g + r1) * DIM + o1;
  const f16* pBl = Wtl + (size_t)(col0g + r1) * DIM + o1;
  const int R64 = 64 * DIM;

  const int frow = lane & 15;
  const int fkb  = (lane >> 4) * 16;

  f32x4 acc[4][4] = {};

  for (int step = 0; step < 16; ++step) {
    const int d0 = step * 32;
    uint4 v0 = *(const uint4*)(pAh + d0);
    uint4 v1 = *(const uint4*)(pAh + R64 + d0);
    uint4 v2 = *(const uint4*)(pAl + d0);
    uint4 v3 = *(const uint4*)(pAl + R64 + d0);
    uint4 v4 = *(const uint4*)(pBh + d0);
    uint4 v5 = *(const uint4*)(pBh + R64 + d0);
    uint4 v6 = *(const uint4*)(pBl + d0);
    uint4 v7 = *(const uint4*)(pBl + R64 + d0);
    __syncthreads();
    *(uint4*)(sm +     0 + sw1) = v0;
    *(uint4*)(sm +     0 + sw2) = v1;
    *(uint4*)(sm +  8192 + sw1) = v2;
    *(uint4*)(sm +  8192 + sw2) = v3;
    *(uint4*)(sm + 16384 + sw1) = v4;
    *(uint4*)(sm + 16384 + sw2) = v5;
    *(uint4*)(sm + 24576 + sw1) = v6;
    *(uint4*)(sm + 24576 + sw2) = v7;
    __syncthreads();
    f16x8 aH[4], aL[4], bH[4], bL[4];
#pragma unroll
    for (int m = 0; m < 4; ++m) {
      int ra = wm + m * 16 + frow;
      int rb = wn + m * 16 + frow;
      int sa = (ra * 64 + fkb) ^ ((ra & 7) << 4);
      int sb = (rb * 64 + fkb) ^ ((rb & 7) << 4);
      aH[m] = *(const f16x8*)(sm +     0 + sa);
      aL[m] = *(const f16x8*)(sm +  8192 + sa);
      bH[m] = *(const f16x8*)(sm + 16384 + sb);
      bL[m] = *(const f16x8*)(sm + 24576 + sb);
    }
#pragma unroll
    for (int m = 0; m < 4; ++m)
#pragma unroll
      for (int n = 0; n < 4; ++n) {
        acc[m][n] = __builtin_amdgcn_mfma_f32_16x16x32_f16(aH[m], bH[n], acc[m][n], 0, 0, 0);
        acc[m][n] = __builtin_amdgcn_mfma_f32_16x16x32_f16(aH[m], bL[n], acc[m][n], 0, 0, 0);
        acc[m][n] = __builtin_amdgcn_mfma_f32_16x16x32_f16(aL[m], bH[n], acc[m][n], 0, 0, 0);
      }
  }

  const int row0 = row0g + wm;
  const int col0 = col0g + wn;
#pragma unroll
  for (int m = 0; m < 4; ++m)
#pragma unroll
    for (int n = 0; n < 4; ++n) {
      int row = row0 + m * 16 + (lane >> 4) * 4;
      int col = col0 + n * 16 + frow;
#pragma unroll
      for (int r = 0; r < 4; ++r) {
        float c = acc[m][n][r] * scale;
        f16 h = (f16)c;
        Oh[(size_t)(row + r) * DIM + col] = h;
        Ol[(size_t)(row + r) * DIM + col] = (f16)(c - (float)h);
      }
    }
}

// ---------------------------------------------------------------------------
// FUSED flash attention (round-3 kernel, two fixes):
//  - __launch_bounds__(512, 1): 256-VGPR cap, no accumulator spills.
//  - 1-D grid with xcd-pinned z decode (z = (bid&7)/pz): each XCD's L2 holds
//    exactly one K/V slice (Z=8 -> ~3.3 MB < 4 MB).
// One block = 8 waves, Q-tile 128 rows, KV-slice = NSEQ/Z in tiles of 128.
// Writes unnormalized O partial ([q][d]) + running m,l per q.
// The z==zout partial lands directly in the output buffer (ws saving).
// ---------------------------------------------------------------------------
__global__ __launch_bounds__(512, 1) void k_flash(
    const f16* __restrict__ Qh, const f16* __restrict__ Ql,
    const f16* __restrict__ Kh, const f16* __restrict__ Kl,
    const f16* __restrict__ XhT,
    float* __restrict__ Opart, float* __restrict__ OutPart, int zout,
    float* __restrict__ mpart, float* __restrict__ lpart, int nt, int Z)
{
  __shared__ __align__(16) char lds[101888];
  char* QKV = lds;                 // 64 KB: QK chunks (4x16KB) / V stage
  char* Pl  = lds + 65536;         // 32 KB: P^T tile [128 q][128 j] f16
  float* m_l  = (float*)(lds + 98304);   // [128]
  float* l_l  = m_l + 128;               // [128]
  float* resc = m_l + 256;               // [128]
  float* redm = m_l + 384;               // [128][2]
  float* reds = m_l + 640;               // [128][2]

  const int tid  = threadIdx.x;
  const int lane = tid & 63;
  const int w    = tid >> 6;
  const int frow = lane & 15;
  const int lhi  = lane >> 4;            // 0..3
  // QK^T wave grid: jw in {0,1} (j 64-range), qw in {0..3} (q 32-range)
  const int jw = w >> 2, qw = w & 3;
  // PV wave grid: qw2 in {0,1} (q 64-range), dw in {0..3} (d 128-range)
  const int qw2 = w >> 2, dw = w & 3;

  // xcd-pinned decode (bijective for Z in {1,2,4,8})
  const int bid = blockIdx.x;
  const int xcd = bid & 7;
  const int pz  = 8 / Z;
  const int z   = xcd / pz;
  const int qb  = ((bid >> 3) * pz + (xcd % pz)) * 128;
  const int j0base = z * nt * 128;

  // ---- staging geometry ----
  int srow[8], slds[8];
#pragma unroll
  for (int g = 0; g < 8; ++g) {
    int idx = (g & 1) * 512 + tid;
    int row = idx >> 3, k16 = idx & 7;
    srow[g] = row;
    slds[g] = (g >> 1) * 16384 + ((row * 128 + k16 * 16) ^ ((row & 7) << 4));
  }
  const int sk8 = (tid & 7) * 8;
  const int vrow = tid >> 1, vhalf = tid & 1;
  int vlds[8];
#pragma unroll
  for (int cc = 0; cc < 8; ++cc)
    vlds[cc] = vrow * 256 + ((vhalf * 128 + cc * 16) ^ ((vrow & 7) << 4));

  uint4 pre[8];

  if (tid < 128) { m_l[tid] = -3.0e38f; l_l[tid] = 0.f; }
  f32x4 accO0[4][4] = {};
  f32x4 accO1[4][4] = {};

  // prologue: prefetch QK chunk 0 of tile 0
#pragma unroll
  for (int g = 0; g < 8; ++g) {
    const f16* bp = (g < 2) ? Qh : (g < 4) ? Ql : (g < 6) ? Kh : Kl;
    int rb = (g < 4) ? qb : j0base;
    pre[g] = *(const uint4*)(bp + (size_t)(rb + srow[g]) * DIM + sk8);
  }

  for (int t = 0; t < nt; ++t) {
    const int j0t = j0base + t * 128;
    f32x4 accS[4][2] = {};

    // ---------------- Phase 1: S^T = K . Q^T over 8 d-chunks ----------------
#pragma unroll
    for (int c = 0; c < 8; ++c) {
      __syncthreads();
#pragma unroll
      for (int g = 0; g < 8; ++g) *(uint4*)(QKV + slds[g]) = pre[g];
      __syncthreads();
      if (c < 7) {
        const int d0 = (c + 1) * 64;
#pragma unroll
        for (int g = 0; g < 8; ++g) {
          const f16* bp = (g < 2) ? Qh : (g < 4) ? Ql : (g < 6) ? Kh : Kl;
          int rb = (g < 4) ? qb : j0t;
          pre[g] = *(const uint4*)(bp + (size_t)(rb + srow[g]) * DIM + d0 + sk8);
        }
      } else {
        const int gd = (vrow >> 6) * 128 + (vrow & 63);
        const f16* bp = XhT + (size_t)gd * VPITCH + j0t + vhalf * 64;
#pragma unroll
        for (int cc = 0; cc < 8; ++cc) pre[cc] = *(const uint4*)(bp + cc * 8);
      }
#pragma unroll
      for (int kk = 0; kk < 2; ++kk) {
        const int kb = kk * 64 + lhi * 16;
        f16x8 ah[4], al[4], bh[2], bl[2];
#pragma unroll
        for (int m = 0; m < 4; ++m) {
          const int jr = jw * 64 + m * 16 + frow;
          const int off = jr * 128 + (kb ^ ((jr & 7) << 4));
          ah[m] = *(const f16x8*)(QKV + 32768 + off);
          al[m] = *(const f16x8*)(QKV + 49152 + off);
        }
#pragma unroll
        for (int n = 0; n < 2; ++n) {
          const int qr = qw * 32 + n * 16 + frow;
          const int off = qr * 128 + (kb ^ ((qr & 7) << 4));
          bh[n] = *(const f16x8*)(QKV + off);
          bl[n] = *(const f16x8*)(QKV + 16384 + off);
        }
#pragma unroll
        for (int m = 0; m < 4; ++m)
#pragma unroll
          for (int n = 0; n < 2; ++n) {
            accS[m][n] = __builtin_amdgcn_mfma_f32_16x16x32_f16(ah[m], bh[n], accS[m][n], 0, 0, 0);
            accS[m][n] = __builtin_amdgcn_mfma_f32_16x16x32_f16(ah[m], bl[n], accS[m][n], 0, 0, 0);
            accS[m][n] = __builtin_amdgcn_mfma_f32_16x16x32_f16(al[m], bh[n], accS[m][n], 0, 0, 0);
          }
      }
    }

    // ---------------- Phase 2: online softmax ----------------
    float cmax[2];
#pragma unroll
    for (int n = 0; n < 2; ++n) {
      float cm = -3.0e38f;
#pragma unroll
      for (int m = 0; m < 4; ++m)
#pragma unroll
        for (int r = 0; r < 4; ++r) cm = fmaxf(cm, accS[m][n][r]);
      cm = fmaxf(cm, __shfl_xor(cm, 16));
      cm = fmaxf(cm, __shfl_xor(cm, 32));
      cmax[n] = cm;
    }
    if (lane < 16) {
      redm[(qw * 32 + lane) * 2 + jw]      = cmax[0];
      redm[(qw * 32 + 16 + lane) * 2 + jw] = cmax[1];
    }
    __syncthreads();
    if (tid < 128) {
      float tm = fmaxf(redm[tid * 2], redm[tid * 2 + 1]);
      float mo = m_l[tid];
      float mn = fmaxf(mo, tm);
      m_l[tid] = mn;
      resc[tid] = __expf(mo - mn);
    }
    __syncthreads();
    float csum[2];
#pragma unroll
    for (int n = 0; n < 2; ++n) {
      const int q = qw * 32 + n * 16 + frow;
      const float mq = m_l[q];
      float cs = 0.f;
#pragma unroll
      for (int m = 0; m < 4; ++m) {
        f16x4 pv;
#pragma unroll
        for (int r = 0; r < 4; ++r) {
          float p = __expf(accS[m][n][r] - mq);
          cs += p;
          pv[r] = (f16)p;
        }
        *(f16x4*)(Pl + ((q * 256 + (jw * 64 + m * 16 + lhi * 4) * 2) ^ ((q & 7) << 4))) = pv;
      }
      cs += __shfl_xor(cs, 16);
      cs += __shfl_xor(cs, 32);
      csum[n] = cs;
    }
    if (lane < 16) {
      reds[(qw * 32 + lane) * 2 + jw]      = csum[0];
      reds[(qw * 32 + 16 + lane) * 2 + jw] = csum[1];
    }
    {
      float rs[4];
#pragma unroll
      for (int n2 = 0; n2 < 4; ++n2) rs[n2] = resc[qw2 * 64 + n2 * 16 + frow];
#pragma unroll
      for (int m2 = 0; m2 < 4; ++m2)
#pragma unroll
        for (int n2 = 0; n2 < 4; ++n2) {
          accO0[m2][n2] *= rs[n2];
          accO1[m2][n2] *= rs[n2];
        }
    }
    __syncthreads();
    if (tid < 128)
      l_l[tid] = l_l[tid] * resc[tid] + reds[tid * 2] + reds[tid * 2 + 1];

    // ---------------- Phase 3: O^T += V . P^T ----------------
#pragma unroll
    for (int cc = 0; cc < 8; ++cc) *(uint4*)(QKV + vlds[cc]) = pre[cc];
    {
      const int gd = (vrow >> 6) * 128 + 64 + (vrow & 63);
      const f16* bp = XhT + (size_t)gd * VPITCH + j0t + vhalf * 64;
#pragma unroll
      for (int cc = 0; cc < 8; ++cc) pre[cc] = *(const uint4*)(bp + cc * 8);
    }
    __syncthreads();
#pragma unroll
    for (int kk = 0; kk < 4; ++kk) {
      const int kb = kk * 64 + lhi * 16;
      f16x8 va[4], pb[4];
#pragma unroll
      for (int m2 = 0; m2 < 4; ++m2) {
        const int dr = dw * 64 + m2 * 16 + frow;
        va[m2] = *(const f16x8*)(QKV + dr * 256 + (kb ^ ((dr & 7) << 4)));
      }
#pragma unroll
      for (int n2 = 0; n2 < 4; ++n2) {
        const int q = qw2 * 64 + n2 * 16 + frow;
        pb[n2] = *(const f16x8*)(Pl + q * 256 + (kb ^ ((q & 7) << 4)));
      }
#pragma unroll
      for (int m2 = 0; m2 < 4; ++m2)
#pragma unroll
        for (int n2 = 0; n2 < 4; ++n2)
          accO0[m2][n2] = __builtin_amdgcn_mfma_f32_16x16x32_f16(va[m2], pb[n2], accO0[m2][n2], 0, 0, 0);
    }
    __syncthreads();
#pragma unroll
    for (int cc = 0; cc < 8; ++cc) *(uint4*)(QKV + vlds[cc]) = pre[cc];
    if (t + 1 < nt) {
#pragma unroll
      for (int g = 0; g < 8; ++g) {
        const f16* bp = (g < 2) ? Qh : (g < 4) ? Ql : (g < 6) ? Kh : Kl;
        int rb = (g < 4) ? qb : (j0t + 128);
        pre[g] = *(const uint4*)(bp + (size_t)(rb + srow[g]) * DIM + sk8);
      }
    }
    __syncthreads();
#pragma unroll
    for (int kk = 0; kk < 4; ++kk) {
      const int kb = kk * 64 + lhi * 16;
      f16x8 va[4], pb[4];
#pragma unroll
      for (int m2 = 0; m2 < 4; ++m2) {
        const int dr = dw * 64 + m2 * 16 + frow;
        va[m2] = *(const f16x8*)(QKV + dr * 256 + (kb ^ ((dr & 7) << 4)));
      }
#pragma unroll
      for (int n2 = 0; n2 < 4; ++n2) {
        const int q = qw2 * 64 + n2 * 16 + frow;
        pb[n2] = *(const f16x8*)(Pl + q * 256 + (kb ^ ((q & 7) << 4)));
      }
#pragma unroll
      for (int m2 = 0; m2 < 4; ++m2)
#pragma unroll
        for (int n2 = 0; n2 < 4; ++n2)
          accO1[m2][n2] = __builtin_amdgcn_mfma_f32_16x16x32_f16(va[m2], pb[n2], accO1[m2][n2], 0, 0, 0);
    }
  }

  // ---------------- epilogue ----------------
  float* op = (z == zout) ? OutPart : (Opart + (size_t)z * NSEQ * DIM);
#pragma unroll
  for (int n2 = 0; n2 < 4; ++n2) {
    const int qg = qb + qw2 * 64 + n2 * 16 + frow;
#pragma unroll
    for (int m2 = 0; m2 < 4; ++m2) {
      const int d0 = dw * 128 + m2 * 16 + lhi * 4;
#pragma unroll
      for (int r = 0; r < 4; ++r) {
        op[(size_t)qg * DIM + d0 + r]      = accO0[m2][n2][r];
        op[(size_t)qg * DIM + d0 + 64 + r] = accO1[m2][n2][r];
      }
    }
  }
  if (tid < 128) {
    mpart[z * NSEQ + qb + tid] = m_l[tid];
    lpart[z * NSEQ + qb + tid] = l_l[tid];
  }
}

// ---------------------------------------------------------------------------
// Combine: Out[q][d] = sum_z e^{m_z-m_g} O_z[q][d] / sum_z e^{m_z-m_g} l_z.
// The z==zout partial is read from OutPart (== Out; read-before-write safe).
// ---------------------------------------------------------------------------
__global__ __launch_bounds__(256) void k_comb(
    const float* __restrict__ Opart, const float* __restrict__ OutPart, int zout,
    const float* __restrict__ mpart, const float* __restrict__ lpart,
    float* __restrict__ Out, int Z)
{
  const int idx = blockIdx.x * 256 + threadIdx.x;
  const int q = idx >> 7;
  const int d4 = idx & 127;
  float mg = -3.0e38f;
  for (int zz = 0; zz < Z; ++zz) mg = fmaxf(mg, mpart[zz * NSEQ + q]);
  f32x4 num = {0.f, 0.f, 0.f, 0.f};
  float den = 0.f;
  for (int zz = 0; zz < Z; ++zz) {
    float wz = __expf(mpart[zz * NSEQ + q] - mg);
    den += wz * lpart[zz * NSEQ + q];
    const float* base = (zz == zout) ? OutPart : (Opart + (size_t)zz * NSEQ * DIM);
    f32x4 v = *(const f32x4*)(base + (size_t)q * DIM + d4 * 4);
    num += v * wz;
  }
  num *= (1.0f / den);
  *(f32x4*)(Out + (size_t)q * DIM + d4 * 4) = num;
}

// ---------------------------------------------------------------------------
extern "C" void kernel_launch(void* const* d_in, const int* in_sizes, int n_in,
                              void* d_out, int out_size, void* d_ws, size_t ws_size,
                              hipStream_t stream) {
  const float* Wq = (const float*)d_in[0];
  const float* Wk = (const float*)d_in[1];
  const float* X  = (const float*)d_in[2];
  float* Out = (float*)d_out;

  char* w = (char*)d_ws;
  const size_t SPLIT  = (size_t)NSEQ * DIM * 2;          // 8 MB
  const size_t XBYTES = (size_t)DIM * VPITCH * 2;        // 8.45 MB
  const size_t WTB    = (size_t)DIM * DIM * 2;           // 512 KB
  f16* Qh  = (f16*)(w);
  f16* Ql  = (f16*)(w + SPLIT);
  f16* Kh  = (f16*)(w + 2 * SPLIT);
  f16* Kl  = (f16*)(w + 3 * SPLIT);
  f16* XhT = (f16*)(w + 4 * SPLIT);
  f16* Xh  = (f16*)(w + 4 * SPLIT + XBYTES);
  f16* Xl  = (f16*)(w + 5 * SPLIT + XBYTES);
  f16* Wth = (f16*)(w + 6 * SPLIT + XBYTES);
  f16* Wtl = (f16*)(w + 6 * SPLIT + XBYTES + WTB);
  float* mpart = (float*)(w + 6 * SPLIT + XBYTES + 2 * WTB);          // 256 KB
  float* lpart = (float*)(w + 6 * SPLIT + XBYTES + 2 * WTB + 262144); // 256 KB
  const size_t used_base = 6 * SPLIT + XBYTES + 2 * WTB + 524288;
  float* Opart = (float*)(w + used_base);
  const size_t OPART1 = (size_t)NSEQ * DIM * 4;          // 16 MB per partial

  const size_t navail = (ws_size > used_base) ? (ws_size - used_base) / OPART1 : 0;
  int Z, zout;
  if      (navail >= 8) { Z = 8; zout = -1; }
  else if (navail >= 7) { Z = 8; zout = 7; }
  else if (navail >= 4) { Z = 4; zout = -1; }
  else if (navail >= 3) { Z = 4; zout = 3; }
  else if (navail >= 2) { Z = 2; zout = -1; }
  else if (navail >= 1) { Z = 2; zout = 1; }
  else                  { Z = 1; zout = 0; }
  const int nt = NSEQ / (Z * 128);

  const float SCALE = 0.044194173824159216f;  // 1/sqrt(512)
  k_splitx<<<NSEQ * DIM / (256 * 4), 256, 0, stream>>>(X, Xh, Xl);
  k_xt<<<dim3(NSEQ / 64, DIM / 64), 256, 0, stream>>>(X, XhT);
  k_splitwt<<<dim3(8, 8), 256, 0, stream>>>(Wq, Wth, Wtl);
  k_proj<<<dim3(NSEQ / 128, DIM / 128), 256, 0, stream>>>(Xh, Xl, Wth, Wtl, Qh, Ql, SCALE);
  k_splitwt<<<dim3(8, 8), 256, 0, stream>>>(Wk, Wth, Wtl);
  k_proj<<<dim3(NSEQ / 128, DIM / 128), 256, 0, stream>>>(Xh, Xl, Wth, Wtl, Kh, Kl, 1.0f);

  k_flash<<<dim3(64 * Z), 512, 0, stream>>>(Qh, Ql, Kh, Kl, XhT,
                                            Opart, Out, zout, mpart, lpart, nt, Z);
  k_comb<<<NSEQ * (DIM / 4) / 256, 256, 0, stream>>>(Opart, Out, zout,
                                                     mpart, lpart, Out, Z);
}

// Round 9
// 654.123 us; speedup vs baseline: 2.1354x; 2.1354x over previous
//
#include <hip/hip_runtime.h>
#include <hip/hip_fp16.h>

#define NSEQ 8192
#define DIM  512
#define SPITCH 8256            // f32 elems per S row / f16 elems per P row
#define SROWB  33024           // bytes per S row

typedef _Float16 f16;
typedef _Float16 f16x8 __attribute__((ext_vector_type(8)));
typedef _Float16 f16x4 __attribute__((ext_vector_type(4)));
typedef float    f32x4 __attribute__((ext_vector_type(4)));

// Fragment-tiled layout (16x32 f16 frags of 512 elems): element (r,k) of a
// (R rows x C k-cols) matrix lives at
//   ((r>>4)*(C>>5) + (k>>5))*512 + (((k>>3)&3)*16 + (r&15))*8 + (k&7)
// MFMA lane l reads its 8 elems as one contiguous 16B chunk at frag+l*8.

// ---------------------------------------------------------------------------
// X (fp32) -> Xh + Xl (f16 hi/lo split), row-major.
// ---------------------------------------------------------------------------
__global__ __launch_bounds__(256) void k_splitx(const float* __restrict__ X,
                                                f16* __restrict__ Xh,
                                                f16* __restrict__ Xl)
{
  const size_t idx = (size_t)blockIdx.x * 256 + threadIdx.x;
  f32x4 v = *(const f32x4*)(X + idx * 4);
  f16x4 h, l;
#pragma unroll
  for (int i = 0; i < 4; ++i) {
    h[i] = (f16)v[i];
    l[i] = (f16)(v[i] - (float)h[i]);
  }
  *(f16x4*)(Xh + idx * 4) = h;
  *(f16x4*)(Xl + idx * 4) = l;
}

// ---------------------------------------------------------------------------
// W (512x512 fp32) -> Wt^T split: Wth/Wtl[c][k] = split(W[k][c]).
// ---------------------------------------------------------------------------
__global__ __launch_bounds__(256) void k_splitwt(const float* __restrict__ W,
                                                 f16* __restrict__ Th,
                                                 f16* __restrict__ Tl)
{
  __shared__ float T[64][65];
  const int tid = threadIdx.x;
  const int k0 = blockIdx.x * 64;
  const int c0 = blockIdx.y * 64;
#pragma unroll
  for (int e = 0; e < 16; ++e) {
    int idx = tid + e * 256;
    T[idx >> 6][idx & 63] = W[(size_t)(k0 + (idx >> 6)) * DIM + c0 + (idx & 63)];
  }
  __syncthreads();
#pragma unroll
  for (int e = 0; e < 16; ++e) {
    int idx = tid + e * 256;
    int cc = idx >> 6, kk = idx & 63;
    float v = T[kk][cc];
    f16 h = (f16)v;
    Th[(size_t)(c0 + cc) * DIM + k0 + kk] = h;
    Tl[(size_t)(c0 + cc) * DIM + k0 + kk] = (f16)(v - (float)h);
  }
}

// ---------------------------------------------------------------------------
// X -> XhTf: frag-tiled V^T (rows = d (512), k-cols = j (8192), C>>5 = 256).
// ---------------------------------------------------------------------------
__global__ __launch_bounds__(256) void k_xt2(const float* __restrict__ X,
                                             f16* __restrict__ XhTf)
{
  __shared__ float T[64][65];
  const int tid = threadIdx.x;
  const int j0 = blockIdx.x * 64;
  const int d0 = blockIdx.y * 64;
#pragma unroll
  for (int e = 0; e < 16; ++e) {
    int idx = tid + e * 256;
    T[idx >> 6][idx & 63] = X[(size_t)(j0 + (idx >> 6)) * DIM + d0 + (idx & 63)];
  }
  __syncthreads();
#pragma unroll
  for (int e = 0; e < 16; ++e) {
    int idx = tid + e * 256;
    int dd = idx >> 6, jj = idx & 63;
    int d = d0 + dd, j = j0 + jj;
    size_t off = ((size_t)(d >> 4) * 256 + (j >> 5)) * 512
               + (((j >> 3) & 3) * 16 + (d & 15)) * 8 + (j & 7);
    XhTf[off] = (f16)T[jj][dd];
  }
}

// ---------------------------------------------------------------------------
// Projection via split-f16 MFMA: C = X W  (M=8192, N=512, K=512).
// 128x128 tile, 4 waves, BK=32, 3-term split, XOR-swizzled LDS.
// Epilogue: c *= scale, split into Oh/Ol row-major (pitch DIM).
// ---------------------------------------------------------------------------
__global__ __launch_bounds__(256) void k_proj(
    const f16* __restrict__ Xh, const f16* __restrict__ Xl,
    const f16* __restrict__ Wth, const f16* __restrict__ Wtl,
    f16* __restrict__ Oh, f16* __restrict__ Ol, float scale)
{
  __shared__ char sm[4 * 8192];
  const int tid  = threadIdx.x;
  const int lane = tid & 63;
  const int w    = tid >> 6;
  const int wm   = (w >> 1) * 64;
  const int wn   = (w & 1) * 64;
  const int row0g = blockIdx.x * 128;
  const int col0g = blockIdx.y * 128;

  const int r1 = tid >> 2;
  const int o1 = (tid & 3) * 8;
  const int sw1 = (r1 * 64 + (tid & 3) * 16) ^ ((r1 & 7) << 4);
  const int sw2 = ((r1 + 64) * 64 + (tid & 3) * 16) ^ (((r1 + 64) & 7) << 4);
  const f16* pAh = Xh  + (size_t)(row0g + r1) * DIM + o1;
  const f16* pAl = Xl  + (size_t)(row0g + r1) * DIM + o1;
  const f16* pBh = Wth + (size_t)(col0g + r1) * DIM + o1;
  const f16* pBl = Wtl + (size_t)(col0g + r1) * DIM + o1;
  const int R64 = 64 * DIM;

  const int frow = lane & 15;
  const int fkb  = (lane >> 4) * 16;

  f32x4 acc[4][4] = {};

  for (int step = 0; step < 16; ++step) {
    const int d0 = step * 32;
    uint4 v0 = *(const uint4*)(pAh + d0);
    uint4 v1 = *(const uint4*)(pAh + R64 + d0);
    uint4 v2 = *(const uint4*)(pAl + d0);
    uint4 v3 = *(const uint4*)(pAl + R64 + d0);
    uint4 v4 = *(const uint4*)(pBh + d0);
    uint4 v5 = *(const uint4*)(pBh + R64 + d0);
    uint4 v6 = *(const uint4*)(pBl + d0);
    uint4 v7 = *(const uint4*)(pBl + R64 + d0);
    __syncthreads();
    *(uint4*)(sm +     0 + sw1) = v0;
    *(uint4*)(sm +     0 + sw2) = v1;
    *(uint4*)(sm +  8192 + sw1) = v2;
    *(uint4*)(sm +  8192 + sw2) = v3;
    *(uint4*)(sm + 16384 + sw1) = v4;
    *(uint4*)(sm + 16384 + sw2) = v5;
    *(uint4*)(sm + 24576 + sw1) = v6;
    *(uint4*)(sm + 24576 + sw2) = v7;
    __syncthreads();
    f16x8 aH[4], aL[4], bH[4], bL[4];
#pragma unroll
    for (int m = 0; m < 4; ++m) {
      int ra = wm + m * 16 + frow;
      int rb = wn + m * 16 + frow;
      int sa = (ra * 64 + fkb) ^ ((ra & 7) << 4);
      int sb = (rb * 64 + fkb) ^ ((rb & 7) << 4);
      aH[m] = *(const f16x8*)(sm +     0 + sa);
      aL[m] = *(const f16x8*)(sm +  8192 + sa);
      bH[m] = *(const f16x8*)(sm + 16384 + sb);
      bL[m] = *(const f16x8*)(sm + 24576 + sb);
    }
#pragma unroll
    for (int m = 0; m < 4; ++m)
#pragma unroll
      for (int n = 0; n < 4; ++n) {
        acc[m][n] = __builtin_amdgcn_mfma_f32_16x16x32_f16(aH[m], bH[n], acc[m][n], 0, 0, 0);
        acc[m][n] = __builtin_amdgcn_mfma_f32_16x16x32_f16(aH[m], bL[n], acc[m][n], 0, 0, 0);
        acc[m][n] = __builtin_amdgcn_mfma_f32_16x16x32_f16(aL[m], bH[n], acc[m][n], 0, 0, 0);
      }
  }

  const int row0 = row0g + wm;
  const int col0 = col0g + wn;
#pragma unroll
  for (int m = 0; m < 4; ++m)
#pragma unroll
    for (int n = 0; n < 4; ++n) {
      int row = row0 + m * 16 + (lane >> 4) * 4;
      int col = col0 + n * 16 + frow;
#pragma unroll
      for (int r = 0; r < 4; ++r) {
        float c = acc[m][n][r] * scale;
        f16 h = (f16)c;
        Oh[(size_t)(row + r) * DIM + col] = h;
        Ol[(size_t)(row + r) * DIM + col] = (f16)(c - (float)h);
      }
    }
}

// ---------------------------------------------------------------------------
// Pass A: S = Q K^T via split-f16 MFMA (3 mfma per fragment pair).
// 128x128 block tile, 4 waves (64x64 each), BK=32, XOR-swizzled LDS.
// ---------------------------------------------------------------------------
__global__ __launch_bounds__(256) void k_qkt(
    const f16* __restrict__ Qh, const f16* __restrict__ Ql,
    const f16* __restrict__ Kh, const f16* __restrict__ Kl,
    float* __restrict__ S, int q0)
{
  __shared__ char sm[4 * 8192];
  const int tid  = threadIdx.x;
  const int lane = tid & 63;
  const int w    = tid >> 6;
  const int wm   = (w >> 1) * 64;
  const int wn   = (w & 1) * 64;
  const int qrow0 = q0 + blockIdx.x * 128;
  const int krow0 = blockIdx.y * 128;

  const int r1 = tid >> 2;
  const int o1 = (tid & 3) * 8;
  const int sw1 = (r1 * 64 + (tid & 3) * 16) ^ ((r1 & 7) << 4);
  const int sw2 = ((r1 + 64) * 64 + (tid & 3) * 16) ^ (((r1 + 64) & 7) << 4);
  const f16* pQh = Qh + (size_t)(qrow0 + r1) * DIM + o1;
  const f16* pQl = Ql + (size_t)(qrow0 + r1) * DIM + o1;
  const f16* pKh = Kh + (size_t)(krow0 + r1) * DIM + o1;
  const f16* pKl = Kl + (size_t)(krow0 + r1) * DIM + o1;
  const int R64 = 64 * DIM;

  const int frow = lane & 15;
  const int fkb  = (lane >> 4) * 16;

  f32x4 acc[4][4] = {};

  for (int step = 0; step < 16; ++step) {
    const int d0 = step * 32;
    uint4 v0 = *(const uint4*)(pQh + d0);
    uint4 v1 = *(const uint4*)(pQh + R64 + d0);
    uint4 v2 = *(const uint4*)(pQl + d0);
    uint4 v3 = *(const uint4*)(pQl + R64 + d0);
    uint4 v4 = *(const uint4*)(pKh + d0);
    uint4 v5 = *(const uint4*)(pKh + R64 + d0);
    uint4 v6 = *(const uint4*)(pKl + d0);
    uint4 v7 = *(const uint4*)(pKl + R64 + d0);
    __syncthreads();
    *(uint4*)(sm +     0 + sw1) = v0;
    *(uint4*)(sm +     0 + sw2) = v1;
    *(uint4*)(sm +  8192 + sw1) = v2;
    *(uint4*)(sm +  8192 + sw2) = v3;
    *(uint4*)(sm + 16384 + sw1) = v4;
    *(uint4*)(sm + 16384 + sw2) = v5;
    *(uint4*)(sm + 24576 + sw1) = v6;
    *(uint4*)(sm + 24576 + sw2) = v7;
    __syncthreads();
    f16x8 aH[4], aL[4], bH[4], bL[4];
#pragma unroll
    for (int m = 0; m < 4; ++m) {
      int ra = wm + m * 16 + frow;
      int rb = wn + m * 16 + frow;
      int sa = (ra * 64 + fkb) ^ ((ra & 7) << 4);
      int sb = (rb * 64 + fkb) ^ ((rb & 7) << 4);
      aH[m] = *(const f16x8*)(sm +     0 + sa);
      aL[m] = *(const f16x8*)(sm +  8192 + sa);
      bH[m] = *(const f16x8*)(sm + 16384 + sb);
      bL[m] = *(const f16x8*)(sm + 24576 + sb);
    }
#pragma unroll
    for (int m = 0; m < 4; ++m)
#pragma unroll
      for (int n = 0; n < 4; ++n) {
        acc[m][n] = __builtin_amdgcn_mfma_f32_16x16x32_f16(aH[m], bH[n], acc[m][n], 0, 0, 0);
        acc[m][n] = __builtin_amdgcn_mfma_f32_16x16x32_f16(aH[m], bL[n], acc[m][n], 0, 0, 0);
        acc[m][n] = __builtin_amdgcn_mfma_f32_16x16x32_f16(aL[m], bH[n], acc[m][n], 0, 0, 0);
      }
  }

  const int srow0 = blockIdx.x * 128 + wm;   // chunk-local S row
  const int scol0 = krow0 + wn;
#pragma unroll
  for (int m = 0; m < 4; ++m)
#pragma unroll
    for (int n = 0; n < 4; ++n) {
      int row = srow0 + m * 16 + (lane >> 4) * 4;
      int col = scol0 + n * 16 + (lane & 15);
#pragma unroll
      for (int r = 0; r < 4; ++r)
        S[(size_t)(row + r) * SPITCH + col] = acc[m][n][r];
    }
}

// ---------------------------------------------------------------------------
// Pass B: one block per row. Row max + sum(exp); writes row-major P (pitch
// SPITCH f16) and the row sum.
// ---------------------------------------------------------------------------
__global__ __launch_bounds__(256) void k_softmax(
    const float* __restrict__ S, f16* __restrict__ P,
    float* __restrict__ Lsum, int q0)
{
  __shared__ float red[4], red2[4];
  const int tid = threadIdx.x;
  const int r = blockIdx.x;
  const float* srow = S + (size_t)r * SPITCH;
  f32x4 v[8];
#pragma unroll
  for (int e = 0; e < 8; ++e)
    v[e] = *(const f32x4*)(srow + (size_t)(tid + e * 256) * 4);
  float m = -3.0e38f;
#pragma unroll
  for (int e = 0; e < 8; ++e)
#pragma unroll
    for (int i = 0; i < 4; ++i) m = fmaxf(m, v[e][i]);
#pragma unroll
  for (int off = 32; off; off >>= 1) m = fmaxf(m, __shfl_xor(m, off));
  if ((tid & 63) == 0) red[tid >> 6] = m;
  __syncthreads();
  m = fmaxf(fmaxf(red[0], red[1]), fmaxf(red[2], red[3]));
  float sum = 0.f;
#pragma unroll
  for (int e = 0; e < 8; ++e)
#pragma unroll
    for (int i = 0; i < 4; ++i) {
      float p = __expf(v[e][i] - m);
      v[e][i] = p;
      sum += p;
    }
#pragma unroll
  for (int off = 32; off; off >>= 1) sum += __shfl_xor(sum, off);
  if ((tid & 63) == 0) red2[tid >> 6] = sum;
  __syncthreads();
  sum = red2[0] + red2[1] + red2[2] + red2[3];
  if (tid == 0) Lsum[q0 + r] = sum;
  f16* prow = P + (size_t)(q0 + r) * SPITCH;
#pragma unroll
  for (int e = 0; e < 8; ++e) {
    f16x4 p;
#pragma unroll
    for (int i = 0; i < 4; ++i) p[i] = (f16)v[e][i];
    *(f16x4*)(prow + (size_t)(tid + e * 256) * 4) = p;
  }
}

// ---------------------------------------------------------------------------
// Pass C: Opart^T = XhTf * P^T.  A = frag-tiled XhTf (coalesced 1KB global
// loads); B = row-major P staged through LDS into frag form (coalesced 128B
// global reads). Block = 4 waves = 32 q x 512 d; 1-D grid 256*Z with
// xcd-pinned z decode. Writes unscaled fp32 partial.
// ---------------------------------------------------------------------------
__global__ __launch_bounds__(256, 2) void k_pv4(
    const f16* __restrict__ XhTf, const f16* __restrict__ P,
    char* __restrict__ obase, size_t qstride, size_t zstride,
    int jrange, int Z)
{
  __shared__ __align__(16) f16 Bl[2][16][512];   // 32 KB: 2 q-groups x 16 j-frags
  const int tid  = threadIdx.x;
  const int lane = tid & 63;
  const int w    = tid >> 6;
  const int frow = lane & 15;
  const int lhi  = lane >> 4;

  const int bid = blockIdx.x;
  const int xcd = bid & 7;
  const int g   = bid >> 3;
  const int pz  = 8 / Z;                        // Z in {1,2,4,8}
  const int z   = xcd / pz;
  const int q0  = (g * pz + (xcd % pz)) * 32;
  const int jbase = z * jrange;
  const int fr0   = jbase >> 5;                 // first global frag col

  // B staging: row = tid>>3 (0..31), seg = tid&7; 8 x 16B per thread covers
  // rows(32) x 512 j. LDS dest: frag = (seg>>2)+e*2, pos = ((seg&3)*16+(row&15))*8.
  const int srow = tid >> 3;
  const int sseg = tid & 7;
  const f16* pB = P + (size_t)(q0 + srow) * SPITCH + jbase + sseg * 8;
  f16* bdst = &Bl[srow >> 4][sseg >> 2][(sseg & 3) * 128 + (srow & 15) * 8];

  // A: frag-direct global. Wave w owns d rows w*128..w*128+127 -> rowgroups w*8+m2.
  const f16* pA = XhTf + (size_t)(w * 8) * 131072 + (size_t)fr0 * 512 + lane * 8;

  f32x4 acc[8][2] = {};
  const int nchunks = jrange / 512;

  uint4 breg[8];
#pragma unroll
  for (int e = 0; e < 8; ++e) breg[e] = *(const uint4*)(pB + e * 64);

  for (int ch = 0; ch < nchunks; ++ch) {
    __syncthreads();                    // prev chunk's LDS reads done
#pragma unroll
    for (int e = 0; e < 8; ++e)
      *(uint4*)(bdst + e * 1024) = breg[e];   // +2 frags = 1024 f16
    __syncthreads();
    if (ch + 1 < nchunks) {
#pragma unroll
      for (int e = 0; e < 8; ++e)
        breg[e] = *(const uint4*)(pB + (ch + 1) * 512 + e * 64);
    }
#pragma unroll 4
    for (int s = 0; s < 16; ++s) {
      const int fc = ch * 16 + s;
      f16x8 b0 = *(const f16x8*)(&Bl[0][s][0] + lane * 8);
      f16x8 b1 = *(const f16x8*)(&Bl[1][s][0] + lane * 8);
#pragma unroll
      for (int m2 = 0; m2 < 8; ++m2) {
        f16x8 a = *(const f16x8*)(pA + (size_t)m2 * 131072 + fc * 512);
        acc[m2][0] = __builtin_amdgcn_mfma_f32_16x16x32_f16(a, b0, acc[m2][0], 0, 0, 0);
        acc[m2][1] = __builtin_amdgcn_mfma_f32_16x16x32_f16(a, b1, acc[m2][1], 0, 0, 0);
      }
    }
  }

  // C row = d = w*128 + m2*16 + lhi*4 + r ; C col = q = q0 + n2*16 + frow
#pragma unroll
  for (int m2 = 0; m2 < 8; ++m2)
#pragma unroll
    for (int n2 = 0; n2 < 2; ++n2) {
      const int qg = q0 + n2 * 16 + frow;
      char* p = obase + (size_t)qg * qstride + (size_t)z * zstride
                      + (size_t)(w * 128 + m2 * 16 + lhi * 4) * 4;
      *(f32x4*)p = acc[m2][n2];
    }
}

// ---------------------------------------------------------------------------
// Pass D: Out[q][d] = (sum_z Opart[z][q][d]) / Lsum[q]. In-place when
// obase==Out (Z==1, zstride==0).
// ---------------------------------------------------------------------------
__global__ __launch_bounds__(256) void k_reduce(
    const char* __restrict__ obase, size_t qstride, size_t zstride, int Z,
    const float* __restrict__ Lsum, float* __restrict__ Out)
{
  const int idx = blockIdx.x * 256 + threadIdx.x;
  const int q = idx >> 7;
  const int d4 = idx & 127;
  const char* p = obase + (size_t)q * qstride + (size_t)d4 * 16;
  f32x4 s = *(const f32x4*)p;
  for (int zz = 1; zz < Z; ++zz)
    s += *(const f32x4*)(p + (size_t)zz * zstride);
  float linv = 1.0f / Lsum[q];
  s *= linv;
  *(f32x4*)(Out + (size_t)q * DIM + d4 * 4) = s;
}

// ---------------------------------------------------------------------------
extern "C" void kernel_launch(void* const* d_in, const int* in_sizes, int n_in,
                              void* d_out, int out_size, void* d_ws, size_t ws_size,
                              hipStream_t stream) {
  const float* Wq = (const float*)d_in[0];
  const float* Wk = (const float*)d_in[1];
  const float* X  = (const float*)d_in[2];
  float* Out = (float*)d_out;

  char* w = (char*)d_ws;
  const size_t SPLIT = (size_t)NSEQ * DIM * 2;           // 8 MB
  const size_t XFB   = (size_t)NSEQ * DIM * 2;           // 8 MB frag XhTf
  const size_t WTB   = (size_t)DIM * DIM * 2;            // 512 KB
  f16* Qh   = (f16*)(w);
  f16* Ql   = (f16*)(w + SPLIT);
  f16* Kh   = (f16*)(w + 2 * SPLIT);
  f16* Kl   = (f16*)(w + 3 * SPLIT);
  f16* XhTf = (f16*)(w + 4 * SPLIT);
  f16* Xh   = (f16*)(w + 4 * SPLIT + XFB);
  f16* Xl   = (f16*)(w + 5 * SPLIT + XFB);
  f16* Wth  = (f16*)(w + 6 * SPLIT + XFB);
  f16* Wtl  = (f16*)(w + 6 * SPLIT + XFB + WTB);
  float* Lsum = (float*)(w + 6 * SPLIT + XFB + 2 * WTB);
  const size_t used_base = 6 * SPLIT + XFB + 2 * WTB + 32768;
  char* rest = w + used_base;
  const size_t PBYTES = (size_t)NSEQ * SPITCH * 2;       // 135.3 MB row P
  const size_t OPART1 = (size_t)NSEQ * DIM * 4;          // 16 MB per partial

  f16* P = (f16*)rest;
  float* S = (float*)(rest + PBYTES);
  size_t avail = (ws_size > used_base + PBYTES) ? ws_size - used_base - PBYTES : 0;
  int CQ = 2048;
  while (CQ > 128 && (size_t)CQ * SROWB > avail) CQ >>= 1;
  size_t schunk = (size_t)CQ * SROWB;
  int zc = (int)(schunk / OPART1);
  int Z = (zc >= 4) ? 4 : (zc >= 2) ? 2 : 1;
  char* obase; size_t qstride = DIM * 4, zstride;
  if (Z >= 2) { obase = (char*)S; zstride = OPART1; }
  else { Z = 1; obase = (char*)Out; zstride = 0; }

  const float SCALE = 0.044194173824159216f;  // 1/sqrt(512)
  k_splitx<<<NSEQ * DIM / (256 * 4), 256, 0, stream>>>(X, Xh, Xl);
  k_xt2<<<dim3(NSEQ / 64, DIM / 64), 256, 0, stream>>>(X, XhTf);
  k_splitwt<<<dim3(8, 8), 256, 0, stream>>>(Wq, Wth, Wtl);
  k_proj<<<dim3(NSEQ / 128, DIM / 128), 256, 0, stream>>>(Xh, Xl, Wth, Wtl, Qh, Ql, SCALE);
  k_splitwt<<<dim3(8, 8), 256, 0, stream>>>(Wk, Wth, Wtl);
  k_proj<<<dim3(NSEQ / 128, DIM / 128), 256, 0, stream>>>(Xh, Xl, Wth, Wtl, Kh, Kl, 1.0f);
  for (int q0 = 0; q0 < NSEQ; q0 += CQ) {
    k_qkt<<<dim3(CQ / 128, NSEQ / 128), 256, 0, stream>>>(Qh, Ql, Kh, Kl, S, q0);
    k_softmax<<<dim3(CQ), 256, 0, stream>>>(S, P, Lsum, q0);
  }
  k_pv4<<<dim3(256 * Z), 256, 0, stream>>>(XhTf, P, obase, qstride, zstride,
                                           NSEQ / Z, Z);
  k_reduce<<<NSEQ * (DIM / 4) / 256, 256, 0, stream>>>(obase, qstride, zstride,
                                                       Z, Lsum, Out);
}